// Round 8
// baseline (139.630 us; speedup 1.0000x reference)
//
#include <hip/hip_runtime.h>
#include <hip/hip_bf16.h>
#include <math.h>

#define BB 16
#define NN 256
#define DD 64
#define KTOP 128

typedef short s16x8 __attribute__((ext_vector_type(8)));
typedef float f32x4 __attribute__((ext_vector_type(4)));

typedef union { s16x8 v; unsigned u[4]; } frag_u;
typedef union { __hip_bfloat162 b2; unsigned u; } cvu;

__device__ __forceinline__ float asf(unsigned u){ union{unsigned u;float f;}c; c.u=u; return c.f; }

// split pair of fp32 into bf16 hi (RNE) + bf16 lo (residual, RNE)
__device__ __forceinline__ void split2(float v0, float v1, unsigned& hu, unsigned& lu) {
    cvu c; c.b2 = __float22bfloat162_rn(make_float2(v0, v1));
    unsigned h = c.u;
    float l0 = v0 - asf(h << 16);
    float l1 = v1 - asf(h & 0xffff0000u);
    c.b2 = __float22bfloat162_rn(make_float2(l0, l1));
    hu = h; lu = c.u;
}

// Fused: logits (split-bf16 MFMA, 3-pass) -> tanh/att_w dot -> softmax -> agg -> h -> score.
// Block = (b, 4 i's), 512 threads / 8 waves; wave w owns j-strip [32w,32w+32).
// ROUND-8 CHANGE: MFMA operands swapped so M-dim = e, N-dim = j:
//   A[m=e][k=d] = x_i[d]*W[d][e]  (the LDS-shared frags — per-lane data unchanged)
//   B[k=d][n=j] = x_j[d]          (per-wave register frags — per-lane data unchanged)
// => C rows = e: the dot over e collapses into the in-register aww*rc fmaf accumulation;
//    only quad-level reduction remains: 2 shfl_xor per jt per ii (was 32 swizzles/ii).
// b_att folded into the MFMA acc init (broadcast ds_read); aww read per-half from LDS.
__global__ __launch_bounds__(512, 6) void k_fused(
    const float* __restrict__ x, const float* __restrict__ W_att,
    const float* __restrict__ b_att, const float* __restrict__ att_w,
    const float* __restrict__ Wpwa, const float* __restrict__ bpwa,
    const float* __restrict__ Wpna, const float* __restrict__ bpna,
    const float* __restrict__ bnsc, const float* __restrict__ bnbi,
    const float* __restrict__ poolw, const float* __restrict__ poolb,
    float* __restrict__ hbuf, float* __restrict__ scores)
{
    const int ig = blockIdx.x;     // 0..63 : i-group of 4
    const int b  = blockIdx.y;     // 0..15
    const int tid = threadIdx.x;
    const int w = tid >> 6, lane = tid & 63;
    const int quad = lane >> 4, c16 = lane & 15;
    const int jb = w * 32;
    const int ibase = ig * 4;

    __shared__ s16x8 sB[2][2][4][2][64]; // [buf][ks][mt][h/l][lane], 32 KB
    __shared__ float sXi[4 * 64];        // the block's 4 x_i rows
    __shared__ float sL[4][256];         // logit rows
    __shared__ float sAgg[4][64];
    __shared__ float sBatt[64];
    __shared__ float sAww[64];

    if (tid < 256) sXi[tid] = x[(b * NN + ibase + (tid >> 6)) * DD + (tid & 63)];
    if (tid < 64) sBatt[tid] = b_att[tid];
    else if (tid < 128) sAww[tid - 64] = att_w[tid - 64];

    const float L2E2 = 2.8853900817779268f;  // 2*log2(e)

    // halfS = 0.5 * sum_e att_w[e]  (tanh = 1-2r algebra; folds the 1/TEMP)
    float halfS;
    {
        float sa = 0.0f;
        #pragma unroll
        for (int mt = 0; mt < 4; ++mt) {
            float4 a4 = ((const float4*)att_w)[mt * 4 + quad];
            sa += (a4.x + a4.y) + (a4.z + a4.w);
        }
        sa += __shfl_xor(sa, 16);
        sa += __shfl_xor(sa, 32);
        halfS = 0.5f * sa;
    }

    const int bks = w >> 2, bmt = w & 3;   // this wave's build task (ks, m-tile of e)

    // X (x_j) fragments, MFMA B operand: B[k=quad*8+t][n=c16] = x[jb+jt*16+c16][ks*32+quad*8+t]
    frag_u Xh[2][2], Xl[2][2];
    #pragma unroll
    for (int jt = 0; jt < 2; ++jt) {
        #pragma unroll
        for (int ks = 0; ks < 2; ++ks) {
            const float* xr = &x[(b * NN + jb + jt * 16 + c16) * DD + ks * 32 + quad * 8];
            float4 a0 = *(const float4*)xr;
            float4 a1 = *(const float4*)(xr + 4);
            split2(a0.x, a0.y, Xh[jt][ks].u[0], Xl[jt][ks].u[0]);
            split2(a0.z, a0.w, Xh[jt][ks].u[1], Xl[jt][ks].u[1]);
            split2(a1.x, a1.y, Xh[jt][ks].u[2], Xl[jt][ks].u[2]);
            split2(a1.z, a1.w, Xh[jt][ks].u[3], Xl[jt][ks].u[3]);
        }
    }
    __syncthreads();   // sXi/sBatt/sAww ready

    // ---- prologue build: ii=0 into buf 0 (A frags: A[m=e][k=d] = x_i[d]*W[d][e]) ----
    {
        const float* xr = &sXi[0 * 64 + bks * 32 + quad * 8];
        float4 c0 = *(const float4*)xr;
        float4 c1 = *(const float4*)(xr + 4);
        float xiv[8] = {c0.x,c0.y,c0.z,c0.w,c1.x,c1.y,c1.z,c1.w};
        const float* wp = &W_att[(bks * 32 + quad * 8) * 64 + bmt * 16 + c16];
        frag_u bh, bl;
        split2(wp[0] * xiv[0], wp[64] * xiv[1], bh.u[0], bl.u[0]);
        split2(wp[128] * xiv[2], wp[192] * xiv[3], bh.u[1], bl.u[1]);
        split2(wp[256] * xiv[4], wp[320] * xiv[5], bh.u[2], bl.u[2]);
        split2(wp[384] * xiv[6], wp[448] * xiv[7], bh.u[3], bl.u[3]);
        sB[0][bks][bmt][0][lane] = bh.v;
        sB[0][bks][bmt][1][lane] = bl.v;
    }

    #pragma unroll
    for (int ii = 0; ii < 4; ++ii) {
        __syncthreads();  // build(ii) visible; compute(ii-1) done -> buf[(ii+1)&1] free

        // ---- build ii+1 into the other buffer (overlaps compute below) ----
        if (ii < 3) {
            const float* xr = &sXi[(ii + 1) * 64 + bks * 32 + quad * 8];
            float4 c0 = *(const float4*)xr;
            float4 c1 = *(const float4*)(xr + 4);
            float xiv[8] = {c0.x,c0.y,c0.z,c0.w,c1.x,c1.y,c1.z,c1.w};
            const float* wp = &W_att[(bks * 32 + quad * 8) * 64 + bmt * 16 + c16];
            frag_u bh, bl;
            split2(wp[0] * xiv[0], wp[64] * xiv[1], bh.u[0], bl.u[0]);
            split2(wp[128] * xiv[2], wp[192] * xiv[3], bh.u[1], bl.u[1]);
            split2(wp[256] * xiv[4], wp[320] * xiv[5], bh.u[2], bl.u[2]);
            split2(wp[384] * xiv[6], wp[448] * xiv[7], bh.u[3], bl.u[3]);
            sB[(ii + 1) & 1][bks][bmt][0][lane] = bh.v;
            sB[(ii + 1) & 1][bks][bmt][1][lane] = bl.v;
        }

        // ---- MFMA + epilogue from buf[ii&1]; m-tiles (e) in two halves, acc = 16 AGPR ----
        const int cur = ii & 1;
        float s0 = 0.0f, s1 = 0.0f;   // per-jt logit partials (sum over in-lane e's)

        #pragma unroll
        for (int eth = 0; eth < 2; ++eth) {
            f32x4 acc[2][2];  // [e2][jt], init with b_att rows (fold bias into matmul)
            #pragma unroll
            for (int e2 = 0; e2 < 2; ++e2) {
                f32x4 bi = *(const f32x4*)&sBatt[(eth * 2 + e2) * 16 + quad * 4];
                acc[e2][0] = bi;
                acc[e2][1] = bi;
            }

            #pragma unroll
            for (int ks = 0; ks < 2; ++ks) {
                #pragma unroll
                for (int e2 = 0; e2 < 2; ++e2) {
                    const int mt = eth * 2 + e2;
                    s16x8 ah = sB[cur][ks][mt][0][lane];
                    s16x8 al = sB[cur][ks][mt][1][lane];
                    #pragma unroll
                    for (int jt = 0; jt < 2; ++jt) {
                        acc[e2][jt] = __builtin_amdgcn_mfma_f32_16x16x32_bf16(ah, Xh[jt][ks].v, acc[e2][jt], 0, 0, 0);
                        acc[e2][jt] = __builtin_amdgcn_mfma_f32_16x16x32_bf16(al, Xh[jt][ks].v, acc[e2][jt], 0, 0, 0);
                        acc[e2][jt] = __builtin_amdgcn_mfma_f32_16x16x32_bf16(ah, Xl[jt][ks].v, acc[e2][jt], 0, 0, 0);
                    }
                }
            }

            // epilogue half: s[jt] += aww[e] * rc, rc = rcp(exp2(L2E2*acc)+1); e-sum is in-register
            #pragma unroll
            for (int e2 = 0; e2 < 2; ++e2) {
                const int mt = eth * 2 + e2;
                f32x4 awwv = *(const f32x4*)&sAww[mt * 16 + quad * 4];
                #pragma unroll
                for (int r = 0; r < 4; ++r) {
                    {
                        float arg = acc[e2][0][r] * L2E2;
                        float m = __builtin_amdgcn_exp2f(arg);
                        float rc = __builtin_amdgcn_rcpf(m + 1.0f);
                        s0 = fmaf(awwv[r], rc, s0);
                    }
                    {
                        float arg = acc[e2][1][r] * L2E2;
                        float m = __builtin_amdgcn_exp2f(arg);
                        float rc = __builtin_amdgcn_rcpf(m + 1.0f);
                        s1 = fmaf(awwv[r], rc, s1);
                    }
                }
            }
        }

        // quad-reduction only (e's fine index is in-lane now); logits*0.5 = halfS - s
        s0 += __shfl_xor(s0, 16);
        s0 += __shfl_xor(s0, 32);
        s1 += __shfl_xor(s1, 16);
        s1 += __shfl_xor(s1, 32);
        if (quad == 0) {
            sL[ii][jb + c16]      = halfS - s0;
            sL[ii][jb + 16 + c16] = halfS - s1;
        }
    }
    __syncthreads();   // sL complete

    // ---- phase 2: wave w<4 does softmax/agg/h/score for i = ibase + w (no barriers) ----
    if (w < 4) {
        const int i = ibase + w;
        float* row = sL[w];
        float lg0 = row[lane], lg1 = row[lane + 64], lg2 = row[lane + 128], lg3 = row[lane + 192];
        float m = fmaxf(fmaxf(lg0, lg1), fmaxf(lg2, lg3));
        #pragma unroll
        for (int off = 32; off; off >>= 1) m = fmaxf(m, __shfl_xor(m, off));
        float e0 = __expf(lg0 - m), e1 = __expf(lg1 - m), e2 = __expf(lg2 - m), e3 = __expf(lg3 - m);
        float ssum = e0 + e1 + e2 + e3;
        #pragma unroll
        for (int off = 32; off; off >>= 1) ssum += __shfl_xor(ssum, off);
        float inv = 1.0f / ssum;
        row[lane] = e0 * inv; row[lane + 64] = e1 * inv;
        row[lane + 128] = e2 * inv; row[lane + 192] = e3 * inv;
        __asm__ volatile("s_waitcnt lgkmcnt(0)" ::: "memory");

        // agg[d]: 4 independent accumulators (breaks the serial fmaf chain)
        float ag0 = 0.f, ag1 = 0.f, ag2 = 0.f, ag3 = 0.f;
        const float4* A4 = (const float4*)row;
        const float* xb = &x[(b * NN) * DD];
        #pragma unroll 8
        for (int jq = 0; jq < 64; ++jq) {
            float4 a = A4[jq];
            int j = jq * 4;
            ag0 = fmaf(a.x, xb[(j + 0) * DD + lane], ag0);
            ag1 = fmaf(a.y, xb[(j + 1) * DD + lane], ag1);
            ag2 = fmaf(a.z, xb[(j + 2) * DD + lane], ag2);
            ag3 = fmaf(a.w, xb[(j + 3) * DD + lane], ag3);
        }
        sAgg[w][lane] = (ag0 + ag1) + (ag2 + ag3);
        __asm__ volatile("s_waitcnt lgkmcnt(0)" ::: "memory");

        double hacc = (double)bpwa[lane] + (double)bpna[lane];
        #pragma unroll 4
        for (int d = 0; d < 64; ++d) {
            hacc += (double)sAgg[w][d] * (double)Wpwa[d * DD + lane]
                  + (double)sXi[w * 64 + d] * (double)Wpna[d * DD + lane];
        }
        const double bnmul = 0.99999500003749968750e0; // 1/sqrt(1+1e-5)
        double hb = hacc * ((double)bnsc[lane] * bnmul) + (double)bnbi[lane];
        float hf = (float)hb;
        const float LAM = 1.0507009873554805f, ALP = 1.6732632423543772f;
        float hs = hf > 0.0f ? LAM * hf : LAM * ALP * (__expf(hf) - 1.0f);
        hbuf[((b * NN) + i) * DD + lane] = hs;

        double z = (double)hs * (double)poolw[lane];
        #pragma unroll
        for (int off = 32; off; off >>= 1) z += __shfl_xor(z, off);
        if (lane == 0) {
            double zz = z + (double)poolb[0];
            scores[b * NN + i] = (float)(1.0 / (1.0 + exp(-zz)));
        }
    }
}

// rank-selection topk, chunked: block (c,b) handles ranks [16c,16c+16) of batch b.
// score desc, tie: lower idx first — matches lax.top_k.
__global__ __launch_bounds__(256) void k_topk(
    const float* __restrict__ scores, const float* __restrict__ hbuf,
    float* __restrict__ out)
{
    const int c = blockIdx.x;   // 0..7
    const int b = blockIdx.y;   // 0..15
    const int t = threadIdx.x;
    __shared__ float ss[256];
    __shared__ int   perm[16];
    ss[t] = scores[b * NN + t];
    __syncthreads();
    const float my = ss[t];
    int rank = 0;
    #pragma unroll 8
    for (int j = 0; j < 256; ++j) {
        float v = ss[j];
        rank += (v > my) || (v == my && j < t);
    }
    if ((rank >> 4) == c) perm[rank & 15] = t;
    __syncthreads();
    #pragma unroll
    for (int m = t; m < 16 * DD; m += 256) {
        int r = m >> 6, e = m & 63;
        int i = perm[r];
        out[(b * KTOP + c * 16 + r) * DD + e] = hbuf[((b * NN) + i) * DD + e] * ss[i];
    }
}

extern "C" void kernel_launch(void* const* d_in, const int* in_sizes, int n_in,
                              void* d_out, int out_size, void* d_ws, size_t ws_size,
                              hipStream_t stream) {
    const float* x        = (const float*)d_in[0];
    const float* W_att    = (const float*)d_in[1];
    const float* b_att    = (const float*)d_in[2];
    const float* att_w    = (const float*)d_in[3];
    const float* W_pwa    = (const float*)d_in[4];
    const float* b_pwa    = (const float*)d_in[5];
    const float* W_pna    = (const float*)d_in[6];
    const float* b_pna    = (const float*)d_in[7];
    const float* bn_scale = (const float*)d_in[8];
    const float* bn_bias  = (const float*)d_in[9];
    const float* pool_w   = (const float*)d_in[10];
    const float* pool_b   = (const float*)d_in[11];

    float* hbuf    = (float*)d_ws;                 // 16*256*64
    float* scoresW = hbuf + BB * NN * DD;          // 16*256
    float* out     = (float*)d_out;

    k_fused<<<dim3(64, BB), 512, 0, stream>>>(x, W_att, b_att, att_w,
                                              W_pwa, b_pwa, W_pna, b_pna,
                                              bn_scale, bn_bias, pool_w, pool_b,
                                              hbuf, scoresW);
    k_topk<<<dim3(8, BB), 256, 0, stream>>>(scoresW, hbuf, out);
}